// Round 4
// baseline (478.306 us; speedup 1.0000x reference)
//
#include <hip/hip_runtime.h>
#include <cstdint>
#include <cstddef>

// ---------- kernel 1: materialize combined weight W [128][512] (f32) ----------
// cols 0..127   = w1_0 rows 0..127   (A1)
// cols 128..255 = w2_0 rows 0..127   (A2)
// cols 256..383 = w1_0 rows 128..255 (B1)
// cols 384..511 = w2_0 rows 128..255 (B2)
__global__ void build_w_kernel(const float* __restrict__ w1_0,
                               const float* __restrict__ w2_0,
                               float* __restrict__ W) {
    int idx = blockIdx.x * blockDim.x + threadIdx.x;
    if (idx >= 128 * 512) return;
    int k = idx >> 9;
    int j = idx & 511;
    float v;
    if (j < 128)      v = w1_0[k * 128 + j];
    else if (j < 256) v = w2_0[k * 128 + (j - 128)];
    else if (j < 384) v = w1_0[(128 + k) * 128 + (j - 256)];
    else              v = w2_0[(128 + k) * 128 + (j - 384)];
    W[idx] = v;
}

// ---------- sort chain: histogram -> scan -> scatter ----------
__global__ void hist_kernel(const int* __restrict__ eidx, int* __restrict__ counts, int E) {
    int e = blockIdx.x * blockDim.x + threadIdx.x;
    if (e < E) atomicAdd(&counts[eidx[e]], 1);
}

__global__ __launch_bounds__(1024) void scan_kernel(const int* __restrict__ counts,
                                                    int* __restrict__ offsets, int N) {
    __shared__ int lds[1024];
    const int t = threadIdx.x;
    const int chunk = (N + 1023) >> 10;
    const int lo = t * chunk;
    const int hi = (lo + chunk < N) ? lo + chunk : N;
    int s = 0;
    for (int i = lo; i < hi; ++i) s += counts[i];
    lds[t] = s;
    __syncthreads();
    int val = s;
    for (int off = 1; off < 1024; off <<= 1) {
        int other = (t >= off) ? lds[t - off] : 0;
        __syncthreads();
        val += other;
        lds[t] = val;
        __syncthreads();
    }
    int run = (t == 0) ? 0 : lds[t - 1];
    for (int i = lo; i < hi; ++i) {
        offsets[i] = run;
        run += counts[i];
    }
}

__global__ void scatter_kernel(const int* __restrict__ eidx,
                               const int* __restrict__ offsets,
                               int* __restrict__ cursor,
                               int* __restrict__ sorted_dst, int E) {
    int e = blockIdx.x * blockDim.x + threadIdx.x;
    if (e >= E) return;
    int s = eidx[e];
    int d = eidx[E + e];
    int p = offsets[s] + atomicAdd(&cursor[s], 1);
    sorted_dst[p] = d;
}

// ---------- kernel 2: GEMM  C[M,512] = X[M,128](f32) @ W[128,512](f32) ----------
// 128x128 tile, 8x8 per thread, BK=32. cols 0..255 -> SRC, 256..511 -> DST.
#define LPAD 4
__global__ __launch_bounds__(256) void gemm_precompute(
    const float* __restrict__ X, const float* __restrict__ W,
    float* __restrict__ SRC, float* __restrict__ DST, int M)
{
    __shared__ float sXT[32][128 + LPAD];   // [k][row]
    __shared__ float sW[32][128 + LPAD];    // [k][col]

    const int tid = threadIdx.x;
    const int bm = blockIdx.x * 128;
    const int bn = blockIdx.y * 128;
    const int ty = tid >> 4;       // 0..15 -> rows ty*8..ty*8+7
    const int tx = tid & 15;       // 0..15 -> cols tx*8..tx*8+7

    const int xr = tid >> 3;       // 0..31
    const int xc = (tid & 7) * 4;  // 0..28
    const int wr = tid >> 5;       // 0..7
    const int wc = (tid & 31) * 4; // 0..124

    float acc[8][8];
#pragma unroll
    for (int i = 0; i < 8; ++i)
#pragma unroll
        for (int j = 0; j < 8; ++j) acc[i][j] = 0.f;

    for (int kt = 0; kt < 128; kt += 32) {
        // X tile: rows bm..bm+127, cols kt..kt+31, stored transposed
#pragma unroll
        for (int q = 0; q < 4; ++q) {
            int row = xr + 32 * q;
            int gr = bm + row;
            float4 v = make_float4(0.f, 0.f, 0.f, 0.f);
            if (gr < M) v = *(const float4*)(X + (size_t)gr * 128 + kt + xc);
            sXT[xc + 0][row] = v.x;
            sXT[xc + 1][row] = v.y;
            sXT[xc + 2][row] = v.z;
            sXT[xc + 3][row] = v.w;
        }
        // W tile: rows kt..kt+31, cols bn..bn+127
#pragma unroll
        for (int q = 0; q < 4; ++q) {
            int row = wr + 8 * q;
            float4 v = *(const float4*)(W + (size_t)(kt + row) * 512 + bn + wc);
            *(float4*)&sW[row][wc] = v;
        }
        __syncthreads();

#pragma unroll
        for (int k = 0; k < 32; ++k) {
            float a[8], b[8];
#pragma unroll
            for (int j = 0; j < 4; ++j) {
                ((float4*)a)[0] = *(const float4*)&sXT[k][ty * 8];
                ((float4*)a)[1] = *(const float4*)&sXT[k][ty * 8 + 4];
                ((float4*)b)[0] = *(const float4*)&sW[k][tx * 8];
                ((float4*)b)[1] = *(const float4*)&sW[k][tx * 8 + 4];
                break;
            }
#pragma unroll
            for (int i = 0; i < 8; ++i)
#pragma unroll
                for (int j = 0; j < 8; ++j)
                    acc[i][j] = fmaf(a[i], b[j], acc[i][j]);
        }
        __syncthreads();
    }

    const int c0 = bn + tx * 8;
#pragma unroll
    for (int i = 0; i < 8; ++i) {
        int gr = bm + ty * 8 + i;
        if (gr >= M) continue;
        float4 v0 = make_float4(acc[i][0], acc[i][1], acc[i][2], acc[i][3]);
        float4 v1 = make_float4(acc[i][4], acc[i][5], acc[i][6], acc[i][7]);
        if (c0 < 256) {
            *(float4*)(SRC + (size_t)gr * 256 + c0) = v0;
            *(float4*)(SRC + (size_t)gr * 256 + c0 + 4) = v1;
        } else {
            *(float4*)(DST + (size_t)gr * 256 + (c0 - 256)) = v0;
            *(float4*)(DST + (size_t)gr * 256 + (c0 - 256) + 4) = v1;
        }
    }
}

// ---------- kernel 3: per-src-node edge processing + fused Gram-Schmidt ----------
// one wave per node; lanes 0..31 handle MLP1 (A1/B1), lanes 32..63 MLP2 (A2/B2)
__global__ __launch_bounds__(256) void edge_group_kernel(
    const int* __restrict__ sorted_dst,
    const int* __restrict__ offsets,
    const int* __restrict__ counts,
    const float* __restrict__ pos,
    const float* __restrict__ SRC,
    const float* __restrict__ DST,
    const float* __restrict__ w1_0, const float* __restrict__ b1_0,
    const float* __restrict__ w1_1, const float* __restrict__ b1_1,
    const float* __restrict__ w2_0, const float* __restrict__ b2_0,
    const float* __restrict__ w2_1, const float* __restrict__ b2_1,
    float* __restrict__ out, int N)
{
    const int lane = threadIdx.x & 63;
    const int n = blockIdx.x * (blockDim.x >> 6) + (threadIdx.x >> 6);
    if (n >= N) return;
    const int half = lane >> 5;
    const int j4 = (lane & 31) * 4;
    const int off128 = half * 128 + j4;

    const float* w0p = half ? w2_0 : w1_0;
    const float* b0p = half ? b2_0 : b1_0;
    const float* w1p = half ? w2_1 : w1_1;

    const float4 wd = *(const float4*)(w0p + 256 * 128 + j4);  // dist-row weights
    const float4 bb = *(const float4*)(b0p + j4);
    const float4 wo = *(const float4*)(w1p + j4);
    const float bias1 = b1_1[0];
    const float bias2 = b2_1[0];

    const float4 a = *(const float4*)(SRC + (size_t)n * 256 + off128);

    const float px = pos[3 * n + 0];
    const float py = pos[3 * n + 1];
    const float pz = pos[3 * n + 2];

    const int beg = offsets[n];
    const int end = beg + counts[n];
    const float inv_cut = 1.0f / 4.5f;

    float a1x = 0.f, a1y = 0.f, a1z = 0.f;
    float a2x = 0.f, a2y = 0.f, a2z = 0.f;

    for (int i = beg; i < end; ++i) {
        const int d = sorted_dst[i];
        const float rx = px - pos[3 * d + 0];
        const float ry = py - pos[3 * d + 1];
        const float rz = pz - pos[3 * d + 2];
        const float dist = sqrtf(rx * rx + ry * ry + rz * rz);

        const float4 b = *(const float4*)(DST + (size_t)d * 256 + off128);

        float h, t = 0.f;
        h = a.x + b.x + fmaf(dist, wd.x, bb.x); t = fmaf(fmaxf(h, 0.f), wo.x, t);
        h = a.y + b.y + fmaf(dist, wd.y, bb.y); t = fmaf(fmaxf(h, 0.f), wo.y, t);
        h = a.z + b.z + fmaf(dist, wd.z, bb.z); t = fmaf(fmaxf(h, 0.f), wo.z, t);
        h = a.w + b.w + fmaf(dist, wd.w, bb.w); t = fmaf(fmaxf(h, 0.f), wo.w, t);

        t += __shfl_xor(t, 1);
        t += __shfl_xor(t, 2);
        t += __shfl_xor(t, 4);
        t += __shfl_xor(t, 8);
        t += __shfl_xor(t, 16);
        const float other = __shfl_xor(t, 32);
        const float m1 = half ? other : t;
        const float m2 = half ? t : other;

        const float mes1 = m1 + bias1;
        const float mes2 = m2 + bias2;

        const float dd = dist * inv_cut;
        const float d2 = dd * dd;
        const float d5 = d2 * d2 * dd;
        const float coe = 1.0f - 21.0f * d5 + 35.0f * d5 * dd - 15.0f * d5 * d2;
        const float w = coe / (dist + 1e-12f);
        const float s1 = mes1 * w;
        const float s2 = mes2 * w;

        a1x = fmaf(rx, s1, a1x); a1y = fmaf(ry, s1, a1y); a1z = fmaf(rz, s1, a1z);
        a2x = fmaf(rx, s2, a2x); a2y = fmaf(ry, s2, a2y); a2z = fmaf(rz, s2, a2z);
    }

    if (lane == 0) {
        float na = sqrtf(a1x * a1x + a1y * a1y + a1z * a1z) + 1e-12f;
        float n1x = a1x / na, n1y = a1y / na, n1z = a1z / na;

        float pr = n1x * a2x + n1y * a2y + n1z * a2z;
        float qx = a2x - pr * n1x, qy = a2y - pr * n1y, qz = a2z - pr * n1z;
        float nq = sqrtf(qx * qx + qy * qy + qz * qz) + 1e-12f;
        float n2x = qx / nq, n2y = qy / nq, n2z = qz / nq;

        float n3x = n1y * n2z - n1z * n2y;
        float n3y = n1z * n2x - n1x * n2z;
        float n3z = n1x * n2y - n1y * n2x;

        float* o = out + (size_t)n * 9;
        o[0] = n1x; o[1] = n1y; o[2] = n1z;
        o[3] = n2x; o[4] = n2y; o[5] = n2z;
        o[6] = n3x; o[7] = n3y; o[8] = n3z;
    }
}

extern "C" void kernel_launch(void* const* d_in, const int* in_sizes, int n_in,
                              void* d_out, int out_size, void* d_ws, size_t ws_size,
                              hipStream_t stream) {
    const float* x    = (const float*)d_in[0];
    const float* pos  = (const float*)d_in[1];
    const int*   eidx = (const int*)d_in[2];
    // d_in[3] = batch (unused)
    const float* w1_0 = (const float*)d_in[4];
    const float* b1_0 = (const float*)d_in[5];
    const float* w1_1 = (const float*)d_in[6];
    const float* b1_1 = (const float*)d_in[7];
    const float* w2_0 = (const float*)d_in[8];
    const float* b2_0 = (const float*)d_in[9];
    const float* w2_1 = (const float*)d_in[10];
    const float* b2_1 = (const float*)d_in[11];

    const int N = in_sizes[0] / 128;
    const int E = in_sizes[2] / 2;

    char* ws = (char*)d_ws;
    float* W          = (float*)ws;                          // 256 KiB
    float* SRC        = (float*)(ws + 128 * 512 * 4);        // N*256 f32
    float* DST        = SRC + (size_t)N * 256;               // N*256 f32
    int*   counts     = (int*)(DST + (size_t)N * 256);       // N
    int*   cursor     = counts + N;                          // N
    int*   offsets    = cursor + N;                          // N
    int*   sorted_dst = offsets + N;                         // E

    // zero counts + cursor
    hipMemsetAsync(counts, 0, (size_t)N * 2 * sizeof(int), stream);

    build_w_kernel<<<(128 * 512 + 255) / 256, 256, 0, stream>>>(w1_0, w2_0, W);

    hist_kernel<<<(E + 255) / 256, 256, 0, stream>>>(eidx, counts, E);
    scan_kernel<<<1, 1024, 0, stream>>>(counts, offsets, N);
    scatter_kernel<<<(E + 255) / 256, 256, 0, stream>>>(eidx, offsets, cursor, sorted_dst, E);

    dim3 gg((N + 127) / 128, 4);
    gemm_precompute<<<gg, 256, 0, stream>>>(x, W, SRC, DST, N);

    edge_group_kernel<<<(N + 3) / 4, 256, 0, stream>>>(
        sorted_dst, offsets, counts, pos, SRC, DST,
        w1_0, b1_0, w1_1, b1_1, w2_0, b2_0, w2_1, b2_1,
        (float*)d_out, N);
}